// Round 7
// baseline (831.972 us; speedup 1.0000x reference)
//
#include <hip/hip_runtime.h>
#include <hip/hip_bf16.h>

#define NHEADS 16
#define HDIM   64
#define MDIM   1024
#define NTOK   121
#define NBATCH 1024

typedef __attribute__((ext_vector_type(4))) float f32x4;
typedef __attribute__((ext_vector_type(4))) short s16x4;
typedef __attribute__((ext_vector_type(8))) short s16x8;

#define WAIT_VM(n)  asm volatile("s_waitcnt vmcnt(" #n ")" ::: "memory")
#define WAIT_LGKM0() asm volatile("s_waitcnt lgkmcnt(0)" ::: "memory")

// f32 -> bf16 RNE (compiler fuses pairs into v_cvt_pk_bf16_f32; m240)
__device__ __forceinline__ short f2bf(float f) {
  __hip_bfloat16 h = __float2bfloat16(f);
  return __builtin_bit_cast(short, h);
}

// ---------------------------------------------------------------------------
// Kernel 0: transpose+convert Wq/Wk/Wv (f32 [k][n]) -> bf16 Wt [n][k] in ws.
// ---------------------------------------------------------------------------
__global__ __launch_bounds__(256) void kTransW(const float* __restrict__ Wq,
                                               const float* __restrict__ Wk,
                                               const float* __restrict__ Wv,
                                               short* __restrict__ Wt) {
  int bid = blockIdx.x;
  int m = bid >> 8, tile = bid & 255;
  int tr = tile >> 4, tc = tile & 15;        // tr: k-tile, tc: n-tile (64x64)
  const float* W = (m == 0) ? Wq : (m == 1) ? Wk : Wv;
  short* T = Wt + (size_t)m * (MDIM * MDIM);
  __shared__ float tl[64][68];
  int t = threadIdx.x;
  int c4 = t & 15, r0 = t >> 4;
#pragma unroll
  for (int i = 0; i < 4; ++i) {
    int kr = r0 + i * 16;
    f32x4 v = *(const f32x4*)(W + (size_t)(tr * 64 + kr) * MDIM + tc * 64 + c4 * 4);
    *(f32x4*)&tl[kr][c4 * 4] = v;
  }
  __syncthreads();
#pragma unroll
  for (int i = 0; i < 4; ++i) {
    int n = r0 + i * 16;
    s16x4 o;
    o.x = f2bf(tl[c4 * 4 + 0][n]);
    o.y = f2bf(tl[c4 * 4 + 1][n]);
    o.z = f2bf(tl[c4 * 4 + 2][n]);
    o.w = f2bf(tl[c4 * 4 + 3][n]);
    *(s16x4*)(T + (size_t)(tc * 64 + n) * MDIM + tr * 64 + c4 * 4) = o;
  }
}

// ---------------------------------------------------------------------------
// 8-wave GEMM core: C[256x256] = A[256 x 1024] * Wt-tile^T, fused f32->bf16 A.
// Round-7: BM=256 doubles MFMA per staging (512 MFMA vs 256 staging ops per
// K-step) -> MFMA:LDS-read ratio matches the m201 template's working point.
// A rows are caller-remapped via rofs[8] (two batches per block for kScores/
// kOut, identity for kQProj); clamped dup rows ignored downstream.
//
// 512 threads = 8 waves (2 wr x 4 wc), wave tile 128x64, acc[8][4]=128 AGPR.
// LDS 96KB: Alds[256x64] single, B 2x[256x64] double-buffered.
// Per K-step (counted drains, no vmcnt(0) in loop — round-6 schedule):
//   issue rHi(kt)                 [B(kt)4, rLo(kt)4, rHi4]
//   vmcnt(4); s_barrier #1        (B(kt)+rLo landed; WAR on Alds; B published)
//   cvt+ds_write rLo | issue B(kt+1)->Bnxt
//   vmcnt(4)                      (rHi landed; B(kt+1) flying)
//   cvt+ds_write rHi | issue rLo(kt+1)
//   lgkmcnt(0); s_barrier #2      (Alds + Bcur ready)
//   MFMA phase: 2 ks x (8 af ds_read + 4 x (bfv ds_read + 8 mfma))
// LDS swizzle both sides: byte ^= (row&7)<<4; B source pre-swizzled chunks.
// ---------------------------------------------------------------------------
__device__ __forceinline__ void gemm_core256(const float* __restrict__ A,
                                             const int rofs[8],
                                             const short* __restrict__ Wt, int c0,
                                             short* Alds, short* Bl0, short* Bl1,
                                             f32x4 acc[8][4], int t) {
  int wid = t >> 6, lane = t & 63;
  int wr = wid >> 2, wc = wid & 3;
  int li = lane & 15, lg = lane >> 4;
  int kq = t & 15, r0s = t >> 4;              // staging: rows r0s+32i, chunk kq
#pragma unroll
  for (int fm = 0; fm < 8; ++fm)
#pragma unroll
    for (int fn = 0; fn < 4; ++fn) acc[fm][fn] = (f32x4)0.0f;

  // prologue: B(0) -> Bl0 and rLo(0)
#pragma unroll
  for (int i = 0; i < 4; ++i) {
    int cl = i * 64 + wid * 8 + (lane >> 3);
    int jg = (lane & 7) ^ (cl & 7);
    const short* g = Wt + (size_t)(c0 + cl) * MDIM + jg * 8;
    short* lb = Bl0 + (i * 64 + wid * 8) * 64;   // wave-uniform base
    __builtin_amdgcn_global_load_lds((const __attribute__((address_space(1))) void*)g,
                                     (__attribute__((address_space(3))) void*)lb,
                                     16, 0, 0);
  }
  f32x4 rLo[4];
#pragma unroll
  for (int i = 0; i < 4; ++i)
    rLo[i] = *(const f32x4*)(A + (size_t)rofs[i] * MDIM + kq * 4);

  for (int kt = 0; kt < 16; ++kt) {
    int k0 = kt * 64;
    short* Bcur = (kt & 1) ? Bl1 : Bl0;
    short* Bnxt = (kt & 1) ? Bl0 : Bl1;
    int kn = (kt < 15) ? k0 + 64 : 0;          // kt=15: dummy in-bounds re-read

    // ---- issue A-hi loads (rows 128..255)
    f32x4 rHi[4];
#pragma unroll
    for (int i = 0; i < 4; ++i)
      rHi[i] = *(const f32x4*)(A + (size_t)rofs[4 + i] * MDIM + k0 + kq * 4);

    WAIT_VM(4);                                // B(kt)+rLo(kt) landed
    __builtin_amdgcn_s_barrier();              // #1 WAR on Alds; B(kt) published
    // ---- cvt + swizzled ds_write: lo rows (0..127)
#pragma unroll
    for (int i = 0; i < 4; ++i) {
      int row = r0s + 32 * i;
      s16x4 b4;
      b4.x = f2bf(rLo[i].x); b4.y = f2bf(rLo[i].y);
      b4.z = f2bf(rLo[i].z); b4.w = f2bf(rLo[i].w);
      int byte = (row * 128 + kq * 8) ^ ((row & 7) << 4);
      *(s16x4*)((char*)Alds + byte) = b4;
    }
    // ---- issue B(kt+1) -> Bnxt (awaited at next loop-top)
#pragma unroll
    for (int i = 0; i < 4; ++i) {
      int cl = i * 64 + wid * 8 + (lane >> 3);
      int jg = (lane & 7) ^ (cl & 7);
      const short* g = Wt + (size_t)(c0 + cl) * MDIM + kn + jg * 8;
      short* lb = Bnxt + (i * 64 + wid * 8) * 64;
      __builtin_amdgcn_global_load_lds((const __attribute__((address_space(1))) void*)g,
                                       (__attribute__((address_space(3))) void*)lb,
                                       16, 0, 0);
    }
    WAIT_VM(4);                                // rHi landed; B(kt+1) flying
    // ---- cvt + ds_write: hi rows (128..255)
#pragma unroll
    for (int i = 0; i < 4; ++i) {
      int row = r0s + 128 + 32 * i;
      s16x4 b4;
      b4.x = f2bf(rHi[i].x); b4.y = f2bf(rHi[i].y);
      b4.z = f2bf(rHi[i].z); b4.w = f2bf(rHi[i].w);
      int byte = (row * 128 + kq * 8) ^ ((row & 7) << 4);
      *(s16x4*)((char*)Alds + byte) = b4;
    }
    // ---- issue rLo(kt+1); latency hidden under MFMA phase
#pragma unroll
    for (int i = 0; i < 4; ++i)
      rLo[i] = *(const f32x4*)(A + (size_t)rofs[i] * MDIM + kn + kq * 4);

    WAIT_LGKM0();                              // A ds_writes complete
    __builtin_amdgcn_s_barrier();              // #2 RAW: Alds + Bcur ready
    // ---- MFMA over the 64-k tile (2 x k=32 steps): 64 mfma/wave
#pragma unroll
    for (int ks = 0; ks < 2; ++ks) {
      int kb = ks * 64 + lg * 16;
      s16x8 af[8];
#pragma unroll
      for (int fm = 0; fm < 8; ++fm) {
        int row = wr * 128 + fm * 16 + li;
        int byte = (row * 128 + kb) ^ ((row & 7) << 4);
        af[fm] = *(s16x8*)((char*)Alds + byte);
      }
#pragma unroll
      for (int fn = 0; fn < 4; ++fn) {
        int col = wc * 64 + fn * 16 + li;
        int byte = (col * 128 + kb) ^ ((col & 7) << 4);
        s16x8 bfv = *(s16x8*)((char*)Bcur + byte);
#pragma unroll
        for (int fm = 0; fm < 8; ++fm)
          acc[fm][fn] = __builtin_amdgcn_mfma_f32_16x16x32_bf16(af[fm], bfv,
                                                                acc[fm][fn], 0, 0, 0);
      }
    }
  }
}

// ---------------------------------------------------------------------------
// q_proj = query @ Wq + bq  -> f32 into d_out's output region (scratch)
// ---------------------------------------------------------------------------
__global__ __launch_bounds__(512, 2) void kQProj(const float* __restrict__ query,
                                                 const short* __restrict__ WtQ,
                                                 const float* __restrict__ bq,
                                                 float* __restrict__ qproj) {
  __shared__ alignas(16) short Alds[256 * 64];
  __shared__ alignas(16) short Bl0[256 * 64];
  __shared__ alignas(16) short Bl1[256 * 64];
  int bid = blockIdx.x;
  int rt = bid >> 2, ct = bid & 3;
  int t = threadIdx.x;
  int r0s = t >> 4;
  int rofs[8];
#pragma unroll
  for (int i = 0; i < 8; ++i) rofs[i] = r0s + 32 * i;
  f32x4 acc[8][4];
  gemm_core256(query + (size_t)rt * 256 * MDIM, rofs, WtQ, ct * 256,
               Alds, Bl0, Bl1, acc, t);
  int wid = t >> 6, lane = t & 63;
  int wr = wid >> 2, wc = wid & 3, li = lane & 15, lg = lane >> 4;
#pragma unroll
  for (int fn = 0; fn < 4; ++fn) {
    int col = ct * 256 + wc * 64 + fn * 16 + li;
    float bqv = bq[col];
#pragma unroll
    for (int fm = 0; fm < 8; ++fm)
#pragma unroll
      for (int rr = 0; rr < 4; ++rr) {
        int row = rt * 256 + wr * 128 + fm * 16 + lg * 4 + rr;
        qproj[(size_t)row * MDIM + col] = acc[fm][fn][rr] + bqv;
      }
  }
}

// ---------------------------------------------------------------------------
// k-GEMM fused with scores + softmax -> writes weights [B,H,121] (f32, d_out)
// block = (batch-pair bp, ct of 256 cols = heads ct*4..ct*4+3)
// wave (wr,wc) owns (batch 2bp+wr, head ct*4+wc) end-to-end.
// ---------------------------------------------------------------------------
__global__ __launch_bounds__(512, 2) void kScores(const float* __restrict__ key,
                                                  const short* __restrict__ WtK,
                                                  const float* __restrict__ bk,
                                                  const float* __restrict__ qproj,
                                                  float* __restrict__ weights) {
  __shared__ alignas(16) short Alds[256 * 64];
  __shared__ alignas(16) short Bl0[256 * 64];
  __shared__ alignas(16) short Bl1[256 * 64];
  __shared__ float s_lds[8][128];
  int bid = blockIdx.x;
  int lbid = (bid & 7) * 256 + (bid >> 3);    // XCD-chunked
  int bp = lbid >> 2, ct = lbid & 3;
  int t = threadIdx.x;
  int r0s = t >> 4;
  int rofs[8];
#pragma unroll
  for (int i = 0; i < 8; ++i) {
    int r = r0s + 32 * i;
    int tok = (r & 127) < NTOK ? (r & 127) : NTOK - 1;   // clamp dup row 120
    rofs[i] = (r < 128 ? 0 : NTOK) + tok;                // 2 batches back-to-back
  }
  f32x4 acc[8][4];
  gemm_core256(key + (size_t)(2 * bp) * NTOK * MDIM, rofs, WtK, ct * 256,
               Alds, Bl0, Bl1, acc, t);
  int wid = t >> 6, lane = t & 63;
  int wr = wid >> 2, wc = wid & 3, li = lane & 15, lg = lane >> 4;
  int b = 2 * bp + wr;
  float qv[4], bkv[4];
#pragma unroll
  for (int fn = 0; fn < 4; ++fn) {
    int col = ct * 256 + wc * 64 + fn * 16 + li;
    qv[fn]  = qproj[(size_t)b * MDIM + col];
    bkv[fn] = bk[col];
  }
#pragma unroll
  for (int fm = 0; fm < 8; ++fm)
#pragma unroll
    for (int rr = 0; rr < 4; ++rr) {
      float p = 0.f;
#pragma unroll
      for (int fn = 0; fn < 4; ++fn) p += (acc[fm][fn][rr] + bkv[fn]) * qv[fn];
      p += __shfl_xor(p, 1); p += __shfl_xor(p, 2);
      p += __shfl_xor(p, 4); p += __shfl_xor(p, 8);
      if (li == 0) {
        int n = fm * 16 + lg * 4 + rr;
        s_lds[wid][n] = p;
      }
    }
  __syncthreads();
  // softmax: wave wid handles (batch 2bp+wr, head ct*4+wc)
  {
    int hg = ct * 4 + wc;
    int n0 = lane, n1 = lane + 64;
    bool v0 = (n0 < NTOK), v1 = (n1 < NTOK);
    float w0, w1;
    if (hg == 0 || hg == 3) {                 // disturb heads: uniform weights
      w0 = 1.f / NTOK; w1 = 1.f / NTOK;
    } else {
      const float kinv = 1.f / 32.f;          // 1/sqrt(d*H)
      float s0 = v0 ? s_lds[wid][n0] * kinv : -1e30f;
      float s1 = v1 ? s_lds[wid][n1] * kinv : -1e30f;
      float m = fmaxf(s0, s1);
#pragma unroll
      for (int msk = 1; msk < 64; msk <<= 1) m = fmaxf(m, __shfl_xor(m, msk));
      float e0 = v0 ? __expf(s0 - m) : 0.f;
      float e1 = v1 ? __expf(s1 - m) : 0.f;
      float s = e0 + e1;
#pragma unroll
      for (int msk = 1; msk < 64; msk <<= 1) s += __shfl_xor(s, msk);
      float inv = 1.f / s;
      w0 = e0 * inv; w1 = e1 * inv;
    }
    float* wp = weights + ((size_t)b * NHEADS + hg) * NTOK;
    if (v0) wp[n0] = w0;
    if (v1) wp[n1] = w1;
  }
}

// ---------------------------------------------------------------------------
// v-GEMM fused with weighted reduction -> output [B, 1024] (f32, d_out)
// ---------------------------------------------------------------------------
__global__ __launch_bounds__(512, 2) void kOut(const float* __restrict__ value,
                                               const short* __restrict__ WtV,
                                               const float* __restrict__ bv,
                                               const float* __restrict__ weights,
                                               float* __restrict__ outp) {
  __shared__ alignas(16) short Alds[256 * 64];
  __shared__ alignas(16) short Bl0[256 * 64];
  __shared__ alignas(16) short Bl1[256 * 64];
  __shared__ float w_lds[8][128];
  int bid = blockIdx.x;
  int lbid = (bid & 7) * 256 + (bid >> 3);
  int bp = lbid >> 2, ct = lbid & 3;
  int t = threadIdx.x;
  // per-wave weight row: wave wid -> (batch 2bp+(wid>>2), head ct*4+(wid&3))
  {
    int w = t >> 6;
    int bb = 2 * bp + (w >> 2), hg = ct * 4 + (w & 3);
    const float* wp = weights + ((size_t)bb * NHEADS + hg) * NTOK;
    int n2 = (t & 63) * 2;
    w_lds[w][n2]     = (n2 < NTOK)     ? wp[n2]     : 0.f;
    w_lds[w][n2 + 1] = (n2 + 1 < NTOK) ? wp[n2 + 1] : 0.f;
  }
  int r0s = t >> 4;
  int rofs[8];
#pragma unroll
  for (int i = 0; i < 8; ++i) {
    int r = r0s + 32 * i;
    int tok = (r & 127) < NTOK ? (r & 127) : NTOK - 1;
    rofs[i] = (r < 128 ? 0 : NTOK) + tok;
  }
  f32x4 acc[8][4];
  gemm_core256(value + (size_t)(2 * bp) * NTOK * MDIM, rofs, WtV, ct * 256,
               Alds, Bl0, Bl1, acc, t);
  int wid = t >> 6, lane = t & 63;
  int wr = wid >> 2, wc = wid & 3, li = lane & 15, lg = lane >> 4;
  int b = 2 * bp + wr;
  float sum4[4] = {0.f, 0.f, 0.f, 0.f};
#pragma unroll
  for (int fm = 0; fm < 8; ++fm)
#pragma unroll
    for (int rr = 0; rr < 4; ++rr) {
      int n = fm * 16 + lg * 4 + rr;
      float wv = w_lds[wid][n];               // 0 for n>=121 (dup rows ignored)
#pragma unroll
      for (int fn = 0; fn < 4; ++fn) sum4[fn] += acc[fm][fn][rr] * wv;
    }
#pragma unroll
  for (int fn = 0; fn < 4; ++fn) {
    sum4[fn] += __shfl_xor(sum4[fn], 16);
    sum4[fn] += __shfl_xor(sum4[fn], 32);
  }
  if (lane < 16) {                            // lg==0 lanes hold the full sum
#pragma unroll
    for (int fn = 0; fn < 4; ++fn) {
      int col = ct * 256 + wc * 64 + fn * 16 + li;
      outp[(size_t)b * MDIM + col] = sum4[fn] + bv[col];
    }
  }
}

// ---------------------------------------------------------------------------
extern "C" void kernel_launch(void* const* d_in, const int* in_sizes, int n_in,
                              void* d_out, int out_size, void* d_ws, size_t ws_size,
                              hipStream_t stream) {
  const float* query = (const float*)d_in[0];
  const float* key   = (const float*)d_in[1];
  const float* value = (const float*)d_in[2];
  const float* Wq    = (const float*)d_in[3];
  const float* bq    = (const float*)d_in[4];
  const float* Wk    = (const float*)d_in[5];
  const float* bk    = (const float*)d_in[6];
  const float* Wv    = (const float*)d_in[7];
  const float* bv    = (const float*)d_in[8];

  float* out     = (float*)d_out;
  float* weights = out + (size_t)NBATCH * MDIM;
  float* qproj   = out;                          // output region reused as scratch

  short* Wt = (short*)d_ws;                      // 3 x 1M bf16 = 6 MB

  kTransW<<<dim3(768),  dim3(256), 0, stream>>>(Wq, Wk, Wv, Wt);
  kQProj <<<dim3(16),   dim3(512), 0, stream>>>(query, Wt, bq, qproj);
  kScores<<<dim3(2048), dim3(512), 0, stream>>>(
      key, Wt + (size_t)MDIM * MDIM, bk, qproj, weights);
  kOut   <<<dim3(2048), dim3(512), 0, stream>>>(
      value, Wt + 2 * (size_t)MDIM * MDIM, bv, weights, out);
}

// Round 8
// 379.183 us; speedup vs baseline: 2.1941x; 2.1941x over previous
//
#include <hip/hip_runtime.h>
#include <hip/hip_bf16.h>

#define NHEADS 16
#define HDIM   64
#define MDIM   1024
#define NTOK   121
#define NBATCH 1024

typedef __attribute__((ext_vector_type(4))) float f32x4;
typedef __attribute__((ext_vector_type(4))) short s16x4;
typedef __attribute__((ext_vector_type(8))) short s16x8;

#define WAIT_VM(n)  asm volatile("s_waitcnt vmcnt(" #n ")" ::: "memory")
#define WAIT_LGKM0() asm volatile("s_waitcnt lgkmcnt(0)" ::: "memory")

// f32 -> bf16 RNE (compiler fuses pairs into v_cvt_pk_bf16_f32; m240)
__device__ __forceinline__ short f2bf(float f) {
  __hip_bfloat16 h = __float2bfloat16(f);
  return __builtin_bit_cast(short, h);
}

#define GLDS(gptr, lptr)                                                        \
  __builtin_amdgcn_global_load_lds(                                             \
      (const __attribute__((address_space(1))) void*)(gptr),                    \
      (__attribute__((address_space(3))) void*)(lptr), 16, 0, 0)

// ---------------------------------------------------------------------------
// Kernel 0: transpose+convert Wq/Wk/Wv (f32 [k][n]) -> bf16 Wt [n][k] in ws.
// WtQ feeds kQProj, WtK feeds kG (its rows j are i-contiguous), WtV feeds kO.
// ---------------------------------------------------------------------------
__global__ __launch_bounds__(256) void kTransW(const float* __restrict__ Wq,
                                               const float* __restrict__ Wk,
                                               const float* __restrict__ Wv,
                                               short* __restrict__ Wt) {
  int bid = blockIdx.x;
  int m = bid >> 8, tile = bid & 255;
  int tr = tile >> 4, tc = tile & 15;
  const float* W = (m == 0) ? Wq : (m == 1) ? Wk : Wv;
  short* T = Wt + (size_t)m * (MDIM * MDIM);
  __shared__ float tl[64][68];
  int t = threadIdx.x;
  int c4 = t & 15, r0 = t >> 4;
#pragma unroll
  for (int i = 0; i < 4; ++i) {
    int kr = r0 + i * 16;
    f32x4 v = *(const f32x4*)(W + (size_t)(tr * 64 + kr) * MDIM + tc * 64 + c4 * 4);
    *(f32x4*)&tl[kr][c4 * 4] = v;
  }
  __syncthreads();
#pragma unroll
  for (int i = 0; i < 4; ++i) {
    int n = r0 + i * 16;
    s16x4 o;
    o.x = f2bf(tl[c4 * 4 + 0][n]);
    o.y = f2bf(tl[c4 * 4 + 1][n]);
    o.z = f2bf(tl[c4 * 4 + 2][n]);
    o.w = f2bf(tl[c4 * 4 + 3][n]);
    *(s16x4*)(T + (size_t)(tc * 64 + n) * MDIM + tr * 64 + c4 * 4) = o;
  }
}

// ---------------------------------------------------------------------------
// Round-6 proven GEMM core (128x128, K=1024), used only for q_proj now.
// ---------------------------------------------------------------------------
__device__ __forceinline__ void gemm_core(const float* __restrict__ A, int mrows,
                                          const short* __restrict__ Wt, int c0,
                                          short* Alds, short* Bl0, short* Bl1,
                                          f32x4 acc[4][4], int t) {
  int wid = t >> 6, lane = t & 63;
  int wr = wid >> 1, wc = wid & 1;
  int li = lane & 15, lg = lane >> 4;
  int kq = t & 15, r0s = t >> 4;
#pragma unroll
  for (int fm = 0; fm < 4; ++fm)
#pragma unroll
    for (int fn = 0; fn < 4; ++fn) acc[fm][fn] = (f32x4)0.0f;

  int rhi[4];
#pragma unroll
  for (int i = 0; i < 4; ++i) {
    int row = r0s + 64 + (i << 4);
    rhi[i] = row < mrows ? row : mrows - 1;
  }
#pragma unroll
  for (int i = 0; i < 4; ++i) {
    int cl = wid * 32 + i * 8 + (lane >> 3);
    int jg = (lane & 7) ^ (cl & 7);
    GLDS(Wt + (size_t)(c0 + cl) * MDIM + jg * 8, Bl0 + (wid * 32 + i * 8) * 64);
  }
  f32x4 rLo[4];
#pragma unroll
  for (int i = 0; i < 4; ++i)
    rLo[i] = *(const f32x4*)(A + (size_t)(r0s + (i << 4)) * MDIM + kq * 4);

  for (int kt = 0; kt < 16; ++kt) {
    int k0 = kt * 64;
    short* Bcur = (kt & 1) ? Bl1 : Bl0;
    short* Bnxt = (kt & 1) ? Bl0 : Bl1;
    int kn = (kt < 15) ? k0 + 64 : 0;

    f32x4 rHi[4];
#pragma unroll
    for (int i = 0; i < 4; ++i)
      rHi[i] = *(const f32x4*)(A + (size_t)rhi[i] * MDIM + k0 + kq * 4);

    WAIT_VM(4);
    __builtin_amdgcn_s_barrier();
#pragma unroll
    for (int i = 0; i < 4; ++i) {
      int row = r0s + (i << 4);
      s16x4 b4;
      b4.x = f2bf(rLo[i].x); b4.y = f2bf(rLo[i].y);
      b4.z = f2bf(rLo[i].z); b4.w = f2bf(rLo[i].w);
      int byte = (row * 128 + kq * 8) ^ ((row & 7) << 4);
      *(s16x4*)((char*)Alds + byte) = b4;
    }
#pragma unroll
    for (int i = 0; i < 4; ++i) {
      int cl = wid * 32 + i * 8 + (lane >> 3);
      int jg = (lane & 7) ^ (cl & 7);
      GLDS(Wt + (size_t)(c0 + cl) * MDIM + kn + jg * 8, Bnxt + (wid * 32 + i * 8) * 64);
    }
    WAIT_VM(4);
#pragma unroll
    for (int i = 0; i < 4; ++i) {
      int row = r0s + 64 + (i << 4);
      s16x4 b4;
      b4.x = f2bf(rHi[i].x); b4.y = f2bf(rHi[i].y);
      b4.z = f2bf(rHi[i].z); b4.w = f2bf(rHi[i].w);
      int byte = (row * 128 + kq * 8) ^ ((row & 7) << 4);
      *(s16x4*)((char*)Alds + byte) = b4;
    }
#pragma unroll
    for (int i = 0; i < 4; ++i)
      rLo[i] = *(const f32x4*)(A + (size_t)(r0s + (i << 4)) * MDIM + kn + kq * 4);

    WAIT_LGKM0();
    __builtin_amdgcn_s_barrier();
#pragma unroll
    for (int ks = 0; ks < 2; ++ks) {
      s16x8 af[4];
      int kb = ks * 64 + lg * 16;
#pragma unroll
      for (int fm = 0; fm < 4; ++fm) {
        int row = wr * 64 + fm * 16 + li;
        int byte = (row * 128 + kb) ^ ((row & 7) << 4);
        af[fm] = *(s16x8*)((char*)Alds + byte);
      }
#pragma unroll
      for (int fn = 0; fn < 4; ++fn) {
        int col = wc * 64 + fn * 16 + li;
        int byte = (col * 128 + kb) ^ ((col & 7) << 4);
        s16x8 bfv = *(s16x8*)((char*)Bcur + byte);
#pragma unroll
        for (int fm = 0; fm < 4; ++fm)
          acc[fm][fn] = __builtin_amdgcn_mfma_f32_16x16x32_bf16(af[fm], bfv,
                                                                acc[fm][fn], 0, 0, 0);
      }
    }
  }
}

// ---------------------------------------------------------------------------
// q_proj = query @ Wq + bq  -> f32 qp[1024x1024] in ws
// ---------------------------------------------------------------------------
__global__ __launch_bounds__(256, 3) void kQProj(const float* __restrict__ query,
                                                 const short* __restrict__ WtQ,
                                                 const float* __restrict__ bq,
                                                 float* __restrict__ qp) {
  __shared__ alignas(16) short Alds[128 * 64];
  __shared__ alignas(16) short Bl0[128 * 64];
  __shared__ alignas(16) short Bl1[128 * 64];
  int bid = blockIdx.x;
  int rt = bid >> 3, ct = bid & 7;
  f32x4 acc[4][4];
  int t = threadIdx.x;
  gemm_core(query + (size_t)rt * 128 * MDIM, 128, WtQ, ct * 128, Alds, Bl0, Bl1, acc, t);
  int wid = t >> 6, lane = t & 63;
  int wr = wid >> 1, wc = wid & 1, li = lane & 15, lg = lane >> 4;
#pragma unroll
  for (int fn = 0; fn < 4; ++fn) {
    int col = ct * 128 + wc * 64 + fn * 16 + li;
    float bqv = bq[col];
#pragma unroll
    for (int fm = 0; fm < 4; ++fm)
#pragma unroll
      for (int rr = 0; rr < 4; ++rr) {
        int row = rt * 128 + wr * 64 + fm * 16 + lg * 4 + rr;
        qp[(size_t)row * MDIM + col] = acc[fm][fn][rr] + bqv;
      }
  }
}

// ---------------------------------------------------------------------------
// kG: g[b,h,i] = sum_{j<64} qp[b, h*64+j] * Wk[i, h*64+j]   (bf16 out, 32MB)
// Per-h GEMM [128b x 64j] x [64j x 128i], K=64 single tile. MFMA 16x16x32.
// B[j][i] = WtK[h*64+j][i] staged TRANSPOSED into Blds[i][j] (swizzled).
// grid = h(16) x bt(8) x it(8) = 1024 blocks, 256 threads.
// ---------------------------------------------------------------------------
__global__ __launch_bounds__(256, 3) void kG(const float* __restrict__ qp,
                                             const short* __restrict__ WtK,
                                             short* __restrict__ g) {
  __shared__ alignas(16) short Alds[128 * 64];
  __shared__ alignas(16) short Blds[128 * 64];
  int bid = blockIdx.x;
  int h = bid >> 6, bt = (bid >> 3) & 7, it = bid & 7;
  int t = threadIdx.x;
  int wid = t >> 6, lane = t & 63;
  int wr = wid >> 1, wc = wid & 1, li = lane & 15, lg = lane >> 4;
  int kq = t & 15, r0s = t >> 4;
  // stage A: qp tile [128 b-rows x 64 j] f32 -> bf16, swizzled
#pragma unroll
  for (int i = 0; i < 8; ++i) {
    int r = r0s + 16 * i;
    f32x4 v = *(const f32x4*)(qp + (size_t)(bt * 128 + r) * MDIM + h * 64 + kq * 4);
    s16x4 b4;
    b4.x = f2bf(v.x); b4.y = f2bf(v.y); b4.z = f2bf(v.z); b4.w = f2bf(v.w);
    int byte = (r * 128 + kq * 8) ^ ((r & 7) << 4);
    *(s16x4*)((char*)Alds + byte) = b4;
  }
  // stage B transposed: Blds[i][j] = WtK[h*64+j][it*128+i]
  {
    int jr = t >> 2, qc = t & 3;
#pragma unroll
    for (int q = 0; q < 4; ++q) {
      s16x8 v = *(const s16x8*)(WtK + (size_t)(h * 64 + jr) * MDIM + it * 128 +
                                qc * 32 + q * 8);
#pragma unroll
      for (int e = 0; e < 8; ++e) {
        int i = qc * 32 + q * 8 + e;
        int byte = (i * 128 + jr * 2) ^ ((i & 7) << 4);
        *(short*)((char*)Blds + byte) = v[e];
      }
    }
  }
  __syncthreads();
  f32x4 acc[4][4];
#pragma unroll
  for (int fm = 0; fm < 4; ++fm)
#pragma unroll
    for (int fn = 0; fn < 4; ++fn) acc[fm][fn] = (f32x4)0.0f;
#pragma unroll
  for (int ks = 0; ks < 2; ++ks) {
    int kb = ks * 64 + lg * 16;
    s16x8 af[4];
#pragma unroll
    for (int fm = 0; fm < 4; ++fm) {
      int row = wr * 64 + fm * 16 + li;
      int byte = (row * 128 + kb) ^ ((row & 7) << 4);
      af[fm] = *(s16x8*)((char*)Alds + byte);
    }
#pragma unroll
    for (int fn = 0; fn < 4; ++fn) {
      int col = wc * 64 + fn * 16 + li;
      int byte = (col * 128 + kb) ^ ((col & 7) << 4);
      s16x8 bfv = *(s16x8*)((char*)Blds + byte);
#pragma unroll
      for (int fm = 0; fm < 4; ++fm)
        acc[fm][fn] = __builtin_amdgcn_mfma_f32_16x16x32_bf16(af[fm], bfv,
                                                              acc[fm][fn], 0, 0, 0);
    }
  }
  // epilogue: g[(b*16+h)*1024 + i] bf16
#pragma unroll
  for (int fm = 0; fm < 4; ++fm)
#pragma unroll
    for (int rr = 0; rr < 4; ++rr) {
      int b = bt * 128 + wr * 64 + fm * 16 + lg * 4 + rr;
      short* gp = g + ((size_t)b * 16 + h) * 1024 + it * 128;
#pragma unroll
      for (int fn = 0; fn < 4; ++fn)
        gp[wc * 64 + fn * 16 + li] = f2bf(acc[fm][fn][rr]);
    }
}

// ---------------------------------------------------------------------------
// kW: per batch b: scores[tok,h] = key[b] (f32->bf16 LDS) x g[b] (bf16 LDS),
// then softmax over tok -> weights (OUTPUT). Memory-bound on key (507MB).
// 512 thr = 8 waves; wave w owns token tile w (16 tokens), N = 16 heads.
// bk dropped: constant per (b,h) -> cancels exactly in softmax (bk==0 anyway).
// ---------------------------------------------------------------------------
__global__ __launch_bounds__(512, 4) void kW(const float* __restrict__ key,
                                             const short* __restrict__ g,
                                             float* __restrict__ weights) {
  __shared__ alignas(16) short Klds[128 * 64];   // 16KB
  __shared__ alignas(16) short Glds[16 * 1024];  // 32KB
  __shared__ float s_lds[16][132];
  int b = blockIdx.x;
  int t = threadIdx.x;
  int wid = t >> 6, lane = t & 63, li = lane & 15, lg = lane >> 4;
  int kq = t & 15, r0s = t >> 4;                 // r0s in [0,32)
  int rcl[4];
#pragma unroll
  for (int i = 0; i < 4; ++i) {
    int r = r0s + 32 * i;
    rcl[i] = r < NTOK ? r : NTOK - 1;
  }
  const float* A = key + (size_t)b * NTOK * MDIM;
  const short* gb = g + (size_t)b * 16384;
  // stage g (bf16) into Glds, swizzled byte ^= (h&7)<<4
#pragma unroll
  for (int q = 0; q < 4; ++q) {
    int c = q * 512 + t;
    s16x8 v = *(const s16x8*)(gb + c * 8);
    int byte = ((c >> 7) * 2048 + (c & 127) * 16) ^ (((c >> 7) & 7) << 4);
    *(s16x8*)((char*)Glds + byte) = v;
  }
  f32x4 rA[4];
#pragma unroll
  for (int i = 0; i < 4; ++i)
    rA[i] = *(const f32x4*)(A + (size_t)rcl[i] * MDIM + kq * 4);
  f32x4 acc = (f32x4)0.0f;

  for (int kt = 0; kt < 16; ++kt) {
    int kn = (kt < 15) ? (kt + 1) * 64 : 0;
    WAIT_VM(0);                                  // rA(kt) landed
    __builtin_amdgcn_s_barrier();                // WAR on Klds
#pragma unroll
    for (int i = 0; i < 4; ++i) {
      int row = r0s + 32 * i;
      s16x4 b4;
      b4.x = f2bf(rA[i].x); b4.y = f2bf(rA[i].y);
      b4.z = f2bf(rA[i].z); b4.w = f2bf(rA[i].w);
      int byte = (row * 128 + kq * 8) ^ ((row & 7) << 4);
      *(s16x4*)((char*)Klds + byte) = b4;
    }
#pragma unroll
    for (int i = 0; i < 4; ++i)
      rA[i] = *(const f32x4*)(A + (size_t)rcl[i] * MDIM + kn + kq * 4);
    WAIT_LGKM0();
    __builtin_amdgcn_s_barrier();                // Klds (and 1st-iter Glds) ready
#pragma unroll
    for (int ks = 0; ks < 2; ++ks) {
      int kb = ks * 64 + lg * 16;
      int row = wid * 16 + li;
      s16x8 af = *(s16x8*)((char*)Klds + ((row * 128 + kb) ^ ((row & 7) << 4)));
      int kel = kt * 64 + ks * 32 + lg * 8;
      s16x8 bf = *(s16x8*)((char*)Glds + ((li * 2048 + kel * 2) ^ ((li & 7) << 4)));
      acc = __builtin_amdgcn_mfma_f32_16x16x32_bf16(af, bf, acc, 0, 0, 0);
    }
  }
  // scatter scores: lane holds tokens wid*16+lg*4+rr for head li
#pragma unroll
  for (int rr = 0; rr < 4; ++rr) s_lds[li][wid * 16 + lg * 4 + rr] = acc[rr];
  __syncthreads();
  // softmax: wave wid handles heads 2wid, 2wid+1
#pragma unroll
  for (int hh = 0; hh < 2; ++hh) {
    int h = wid * 2 + hh;
    int n0 = lane, n1 = lane + 64;
    bool v0 = (n0 < NTOK), v1 = (n1 < NTOK);
    float w0, w1;
    if (h == 0 || h == 3) {                      // disturb heads: uniform
      w0 = 1.f / NTOK; w1 = 1.f / NTOK;
    } else {
      const float kinv = 1.f / 32.f;             // 1/sqrt(d*H)
      float s0 = v0 ? s_lds[h][n0] * kinv : -1e30f;
      float s1 = v1 ? s_lds[h][n1] * kinv : -1e30f;
      float m = fmaxf(s0, s1);
#pragma unroll
      for (int msk = 1; msk < 64; msk <<= 1) m = fmaxf(m, __shfl_xor(m, msk));
      float e0 = v0 ? __expf(s0 - m) : 0.f;
      float e1 = v1 ? __expf(s1 - m) : 0.f;
      float s = e0 + e1;
#pragma unroll
      for (int msk = 1; msk < 64; msk <<= 1) s += __shfl_xor(s, msk);
      float inv = 1.f / s;
      w0 = e0 * inv; w1 = e1 * inv;
    }
    float* wp = weights + ((size_t)b * NHEADS + h) * NTOK;
    if (v0) wp[n0] = w0;
    if (v1) wp[n1] = w1;
  }
}

// ---------------------------------------------------------------------------
// kV: vbar[b,h,i] = sum_n weights[b,h,n] * value[b,n,i]  (f32, 64MB in ws)
// Streaming value (507MB). 512 thr: group g=t>>7 owns heads 4g..4g+3,
// i-chunk c=t&127 owns i in [8c, 8c+8). 32 f32 acc/thread.
// ---------------------------------------------------------------------------
__global__ __launch_bounds__(512, 4) void kV(const float* __restrict__ value,
                                             const float* __restrict__ weights,
                                             float* __restrict__ vbar) {
  __shared__ float w_lds[16][128];
  int b = blockIdx.x;
  int t = threadIdx.x;
  int grp = t >> 7, ic = t & 127;
#pragma unroll
  for (int q = 0; q < 4; ++q) {
    int idx = q * 512 + t;
    int h = idx >> 7, n = idx & 127;
    w_lds[h][n] = (n < NTOK) ? weights[((size_t)b * NHEADS + h) * NTOK + n] : 0.f;
  }
  __syncthreads();
  const float* V = value + (size_t)b * NTOK * MDIM;
  f32x4 a0[4], a1[4];
#pragma unroll
  for (int hh = 0; hh < 4; ++hh) { a0[hh] = (f32x4)0.0f; a1[hh] = (f32x4)0.0f; }
#pragma unroll 2
  for (int n = 0; n < NTOK; ++n) {
    f32x4 v0 = *(const f32x4*)(V + (size_t)n * MDIM + ic * 8);
    f32x4 v1 = *(const f32x4*)(V + (size_t)n * MDIM + ic * 8 + 4);
#pragma unroll
    for (int hh = 0; hh < 4; ++hh) {
      float wn = w_lds[grp * 4 + hh][n];
      a0[hh] += wn * v0;
      a1[hh] += wn * v1;
    }
  }
#pragma unroll
  for (int hh = 0; hh < 4; ++hh) {
    float* vp = vbar + ((size_t)b * 16 + grp * 4 + hh) * 1024 + ic * 8;
    *(f32x4*)vp = a0[hh];
    *(f32x4*)(vp + 4) = a1[hh];
  }
}

// ---------------------------------------------------------------------------
// kO: out[b, h*64+c] = sum_i vbar[b,h,i] * Wv[i, h*64+c] + bv  (bf16 MFMA)
// Round-4-style core, BM=128 (b-rows, fixed h), BN=64, K=1024.
// grid = bt(8) x h(16) = 128 blocks, 256 threads.
// ---------------------------------------------------------------------------
__global__ __launch_bounds__(256, 3) void kO(const float* __restrict__ vbar,
                                             const short* __restrict__ WtV,
                                             const float* __restrict__ bv,
                                             float* __restrict__ outp) {
  __shared__ alignas(16) short Alds[128 * 64];
  __shared__ alignas(16) short Blds[64 * 64];
  int bid = blockIdx.x;
  int bt = bid >> 4, h = bid & 15;
  int t = threadIdx.x;
  int wid = t >> 6, lane = t & 63;
  int wr = wid >> 1, wc = wid & 1, li = lane & 15, lg = lane >> 4;
  int kq = t & 15, r0s = t >> 4;
  const float* A = vbar + (size_t)bt * 128 * 16384 + (size_t)h * 1024; // +r*16384
  f32x4 acc[4][2];
#pragma unroll
  for (int fm = 0; fm < 4; ++fm)
#pragma unroll
    for (int fn = 0; fn < 2; ++fn) acc[fm][fn] = (f32x4)0.0f;
  f32x4 rLo[4];
#pragma unroll
  for (int i = 0; i < 4; ++i)
    rLo[i] = *(const f32x4*)(A + (size_t)(r0s + 16 * i) * 16384 + kq * 4);

  for (int kt = 0; kt < 16; ++kt) {
    int k0 = kt * 64;
    __syncthreads();
    f32x4 rHi[4];
#pragma unroll
    for (int i = 0; i < 4; ++i)
      rHi[i] = *(const f32x4*)(A + (size_t)(r0s + 64 + 16 * i) * 16384 + k0 + kq * 4);
#pragma unroll
    for (int j = 0; j < 2; ++j) {
      int cl = wid * 16 + j * 8 + (lane >> 3);
      int jg = (lane & 7) ^ (cl & 7);
      GLDS(WtV + (size_t)(h * 64 + cl) * MDIM + k0 + jg * 8,
           Blds + (wid * 16 + j * 8) * 64);
    }
#pragma unroll
    for (int i = 0; i < 4; ++i) {
      int row = r0s + 16 * i;
      s16x4 b4;
      b4.x = f2bf(rLo[i].x); b4.y = f2bf(rLo[i].y);
      b4.z = f2bf(rLo[i].z); b4.w = f2bf(rLo[i].w);
      int byte = (row * 128 + kq * 8) ^ ((row & 7) << 4);
      *(s16x4*)((char*)Alds + byte) = b4;
    }
#pragma unroll
    for (int i = 0; i < 4; ++i) {
      int row = r0s + 64 + 16 * i;
      s16x4 b4;
      b4.x = f2bf(rHi[i].x); b4.y = f2bf(rHi[i].y);
      b4.z = f2bf(rHi[i].z); b4.w = f2bf(rHi[i].w);
      int byte = (row * 128 + kq * 8) ^ ((row & 7) << 4);
      *(s16x4*)((char*)Alds + byte) = b4;
    }
    __syncthreads();
    {
      int k1 = (kt < 15) ? k0 + 64 : 0;
#pragma unroll
      for (int i = 0; i < 4; ++i)
        rLo[i] = *(const f32x4*)(A + (size_t)(r0s + 16 * i) * 16384 + k1 + kq * 4);
    }
#pragma unroll
    for (int ks = 0; ks < 2; ++ks) {
      int kb = ks * 64 + lg * 16;
      s16x8 af[4];
#pragma unroll
      for (int fm = 0; fm < 4; ++fm) {
        int row = wr * 64 + fm * 16 + li;
        int byte = (row * 128 + kb) ^ ((row & 7) << 4);
        af[fm] = *(s16x8*)((char*)Alds + byte);
      }
#pragma unroll
      for (int fn = 0; fn < 2; ++fn) {
        int col = wc * 32 + fn * 16 + li;
        int byte = (col * 128 + kb) ^ ((col & 7) << 4);
        s16x8 bfv = *(s16x8*)((char*)Blds + byte);
#pragma unroll
        for (int fm = 0; fm < 4; ++fm)
          acc[fm][fn] = __builtin_amdgcn_mfma_f32_16x16x32_bf16(af[fm], bfv,
                                                                acc[fm][fn], 0, 0, 0);
      }
    }
  }
#pragma unroll
  for (int fn = 0; fn < 2; ++fn) {
    int cg = h * 64 + wc * 32 + fn * 16 + li;
    float bvv = bv[cg];
#pragma unroll
    for (int fm = 0; fm < 4; ++fm)
#pragma unroll
      for (int rr = 0; rr < 4; ++rr) {
        int row = bt * 128 + wr * 64 + fm * 16 + lg * 4 + rr;
        outp[(size_t)row * MDIM + cg] = acc[fm][fn][rr] + bvv;
      }
  }
}

// ---------------------------------------------------------------------------
extern "C" void kernel_launch(void* const* d_in, const int* in_sizes, int n_in,
                              void* d_out, int out_size, void* d_ws, size_t ws_size,
                              hipStream_t stream) {
  const float* query = (const float*)d_in[0];
  const float* key   = (const float*)d_in[1];
  const float* value = (const float*)d_in[2];
  const float* Wq    = (const float*)d_in[3];
  const float* bq    = (const float*)d_in[4];
  const float* Wk    = (const float*)d_in[5];
  const float* bk    = (const float*)d_in[6];  // cancels in softmax (constant/row)
  const float* Wv    = (const float*)d_in[7];
  const float* bv    = (const float*)d_in[8];
  (void)bk;

  float* out     = (float*)d_out;
  float* weights = out + (size_t)NBATCH * MDIM;

  // ws layout (ws_size >= 490MB established in round 2):
  char* ws = (char*)d_ws;
  short* Wt   = (short*)ws;                               // 6 MB (3x bf16 1Kx1K)
  float* qp   = (float*)(ws + 6u  * 1024 * 1024);         // 4 MB
  short* g    = (short*)(ws + 10u * 1024 * 1024);         // 32 MB bf16
  float* vbar = (float*)(ws + 48u * 1024 * 1024);         // 64 MB

  kTransW<<<dim3(768),  dim3(256), 0, stream>>>(Wq, Wk, Wv, Wt);
  kQProj <<<dim3(64),   dim3(256), 0, stream>>>(query, Wt, bq, qp);
  kG     <<<dim3(1024), dim3(256), 0, stream>>>(qp, Wt + (size_t)MDIM * MDIM, g);
  kW     <<<dim3(1024), dim3(512), 0, stream>>>(key, g, weights);
  kV     <<<dim3(1024), dim3(512), 0, stream>>>(value, weights, vbar);
  kO     <<<dim3(128),  dim3(256), 0, stream>>>(vbar, Wt + 2 * (size_t)MDIM * MDIM,
                                                bv, out);
}

// Round 9
// 314.969 us; speedup vs baseline: 2.6414x; 1.2039x over previous
//
#include <hip/hip_runtime.h>
#include <hip/hip_bf16.h>

#define NHEADS 16
#define HDIM   64
#define MDIM   1024
#define NTOK   121
#define NBATCH 1024

typedef __attribute__((ext_vector_type(4))) float f32x4;
typedef __attribute__((ext_vector_type(4))) short s16x4;
typedef __attribute__((ext_vector_type(8))) short s16x8;

#define WAIT_VM(n)  asm volatile("s_waitcnt vmcnt(" #n ")" ::: "memory")
#define WAIT_LGKM0() asm volatile("s_waitcnt lgkmcnt(0)" ::: "memory")

// f32 -> bf16 RNE (compiler fuses pairs into v_cvt_pk_bf16_f32; m240)
__device__ __forceinline__ short f2bf(float f) {
  __hip_bfloat16 h = __float2bfloat16(f);
  return __builtin_bit_cast(short, h);
}

#define GLDS(gptr, lptr)                                                        \
  __builtin_amdgcn_global_load_lds(                                             \
      (const __attribute__((address_space(1))) void*)(gptr),                    \
      (__attribute__((address_space(3))) void*)(lptr), 16, 0, 0)

// ---------------------------------------------------------------------------
// Kernel 0: transpose+convert Wq/Wk/Wv (f32 [k][n]) -> bf16 Wt [n][k] in ws.
// ---------------------------------------------------------------------------
__global__ __launch_bounds__(256) void kTransW(const float* __restrict__ Wq,
                                               const float* __restrict__ Wk,
                                               const float* __restrict__ Wv,
                                               short* __restrict__ Wt) {
  int bid = blockIdx.x;
  int m = bid >> 8, tile = bid & 255;
  int tr = tile >> 4, tc = tile & 15;
  const float* W = (m == 0) ? Wq : (m == 1) ? Wk : Wv;
  short* T = Wt + (size_t)m * (MDIM * MDIM);
  __shared__ float tl[64][68];
  int t = threadIdx.x;
  int c4 = t & 15, r0 = t >> 4;
#pragma unroll
  for (int i = 0; i < 4; ++i) {
    int kr = r0 + i * 16;
    f32x4 v = *(const f32x4*)(W + (size_t)(tr * 64 + kr) * MDIM + tc * 64 + c4 * 4);
    *(f32x4*)&tl[kr][c4 * 4] = v;
  }
  __syncthreads();
#pragma unroll
  for (int i = 0; i < 4; ++i) {
    int n = r0 + i * 16;
    s16x4 o;
    o.x = f2bf(tl[c4 * 4 + 0][n]);
    o.y = f2bf(tl[c4 * 4 + 1][n]);
    o.z = f2bf(tl[c4 * 4 + 2][n]);
    o.w = f2bf(tl[c4 * 4 + 3][n]);
    *(s16x4*)(T + (size_t)(tc * 64 + n) * MDIM + tr * 64 + c4 * 4) = o;
  }
}

// ---------------------------------------------------------------------------
// Round-6 proven GEMM core (128x128, K=1024) — q_proj only.
// ---------------------------------------------------------------------------
__device__ __forceinline__ void gemm_core(const float* __restrict__ A, int mrows,
                                          const short* __restrict__ Wt, int c0,
                                          short* Alds, short* Bl0, short* Bl1,
                                          f32x4 acc[4][4], int t) {
  int wid = t >> 6, lane = t & 63;
  int wr = wid >> 1, wc = wid & 1;
  int li = lane & 15, lg = lane >> 4;
  int kq = t & 15, r0s = t >> 4;
#pragma unroll
  for (int fm = 0; fm < 4; ++fm)
#pragma unroll
    for (int fn = 0; fn < 4; ++fn) acc[fm][fn] = (f32x4)0.0f;

  int rhi[4];
#pragma unroll
  for (int i = 0; i < 4; ++i) {
    int row = r0s + 64 + (i << 4);
    rhi[i] = row < mrows ? row : mrows - 1;
  }
#pragma unroll
  for (int i = 0; i < 4; ++i) {
    int cl = wid * 32 + i * 8 + (lane >> 3);
    int jg = (lane & 7) ^ (cl & 7);
    GLDS(Wt + (size_t)(c0 + cl) * MDIM + jg * 8, Bl0 + (wid * 32 + i * 8) * 64);
  }
  f32x4 rLo[4];
#pragma unroll
  for (int i = 0; i < 4; ++i)
    rLo[i] = *(const f32x4*)(A + (size_t)(r0s + (i << 4)) * MDIM + kq * 4);

  for (int kt = 0; kt < 16; ++kt) {
    int k0 = kt * 64;
    short* Bcur = (kt & 1) ? Bl1 : Bl0;
    short* Bnxt = (kt & 1) ? Bl0 : Bl1;
    int kn = (kt < 15) ? k0 + 64 : 0;

    f32x4 rHi[4];
#pragma unroll
    for (int i = 0; i < 4; ++i)
      rHi[i] = *(const f32x4*)(A + (size_t)rhi[i] * MDIM + k0 + kq * 4);

    WAIT_VM(4);
    __builtin_amdgcn_s_barrier();
#pragma unroll
    for (int i = 0; i < 4; ++i) {
      int row = r0s + (i << 4);
      s16x4 b4;
      b4.x = f2bf(rLo[i].x); b4.y = f2bf(rLo[i].y);
      b4.z = f2bf(rLo[i].z); b4.w = f2bf(rLo[i].w);
      int byte = (row * 128 + kq * 8) ^ ((row & 7) << 4);
      *(s16x4*)((char*)Alds + byte) = b4;
    }
#pragma unroll
    for (int i = 0; i < 4; ++i) {
      int cl = wid * 32 + i * 8 + (lane >> 3);
      int jg = (lane & 7) ^ (cl & 7);
      GLDS(Wt + (size_t)(c0 + cl) * MDIM + kn + jg * 8, Bnxt + (wid * 32 + i * 8) * 64);
    }
    WAIT_VM(4);
#pragma unroll
    for (int i = 0; i < 4; ++i) {
      int row = r0s + 64 + (i << 4);
      s16x4 b4;
      b4.x = f2bf(rHi[i].x); b4.y = f2bf(rHi[i].y);
      b4.z = f2bf(rHi[i].z); b4.w = f2bf(rHi[i].w);
      int byte = (row * 128 + kq * 8) ^ ((row & 7) << 4);
      *(s16x4*)((char*)Alds + byte) = b4;
    }
#pragma unroll
    for (int i = 0; i < 4; ++i)
      rLo[i] = *(const f32x4*)(A + (size_t)(r0s + (i << 4)) * MDIM + kn + kq * 4);

    WAIT_LGKM0();
    __builtin_amdgcn_s_barrier();
#pragma unroll
    for (int ks = 0; ks < 2; ++ks) {
      s16x8 af[4];
      int kb = ks * 64 + lg * 16;
#pragma unroll
      for (int fm = 0; fm < 4; ++fm) {
        int row = wr * 64 + fm * 16 + li;
        int byte = (row * 128 + kb) ^ ((row & 7) << 4);
        af[fm] = *(s16x8*)((char*)Alds + byte);
      }
#pragma unroll
      for (int fn = 0; fn < 4; ++fn) {
        int col = wc * 64 + fn * 16 + li;
        int byte = (col * 128 + kb) ^ ((col & 7) << 4);
        s16x8 bfv = *(s16x8*)((char*)Bcur + byte);
#pragma unroll
        for (int fm = 0; fm < 4; ++fm)
          acc[fm][fn] = __builtin_amdgcn_mfma_f32_16x16x32_bf16(af[fm], bfv,
                                                                acc[fm][fn], 0, 0, 0);
      }
    }
  }
}

// ---------------------------------------------------------------------------
// q_proj = query @ Wq + bq  -> f32 qp[1024x1024] in ws
// ---------------------------------------------------------------------------
__global__ __launch_bounds__(256, 3) void kQProj(const float* __restrict__ query,
                                                 const short* __restrict__ WtQ,
                                                 const float* __restrict__ bq,
                                                 float* __restrict__ qp) {
  __shared__ alignas(16) short Alds[128 * 64];
  __shared__ alignas(16) short Bl0[128 * 64];
  __shared__ alignas(16) short Bl1[128 * 64];
  int bid = blockIdx.x;
  int rt = bid >> 3, ct = bid & 7;
  f32x4 acc[4][4];
  int t = threadIdx.x;
  gemm_core(query + (size_t)rt * 128 * MDIM, 128, WtQ, ct * 128, Alds, Bl0, Bl1, acc, t);
  int wid = t >> 6, lane = t & 63;
  int wr = wid >> 1, wc = wid & 1, li = lane & 15, lg = lane >> 4;
#pragma unroll
  for (int fn = 0; fn < 4; ++fn) {
    int col = ct * 128 + wc * 64 + fn * 16 + li;
    float bqv = bq[col];
#pragma unroll
    for (int fm = 0; fm < 4; ++fm)
#pragma unroll
      for (int rr = 0; rr < 4; ++rr) {
        int row = rt * 128 + wr * 64 + fm * 16 + lg * 4 + rr;
        qp[(size_t)row * MDIM + col] = acc[fm][fn][rr] + bqv;
      }
  }
}

// ---------------------------------------------------------------------------
// kG: g[b,h,i] = sum_{j<64} qp[b, h*64+j] * Wk[i, h*64+j]   (bf16 out, 32MB)
// ---------------------------------------------------------------------------
__global__ __launch_bounds__(256, 3) void kG(const float* __restrict__ qp,
                                             const short* __restrict__ WtK,
                                             short* __restrict__ g) {
  __shared__ alignas(16) short Alds[128 * 64];
  __shared__ alignas(16) short Blds[128 * 64];
  int bid = blockIdx.x;
  int h = bid >> 6, bt = (bid >> 3) & 7, it = bid & 7;
  int t = threadIdx.x;
  int wid = t >> 6, lane = t & 63;
  int wr = wid >> 1, wc = wid & 1, li = lane & 15, lg = lane >> 4;
  int kq = t & 15, r0s = t >> 4;
#pragma unroll
  for (int i = 0; i < 8; ++i) {
    int r = r0s + 16 * i;
    f32x4 v = *(const f32x4*)(qp + (size_t)(bt * 128 + r) * MDIM + h * 64 + kq * 4);
    s16x4 b4;
    b4.x = f2bf(v.x); b4.y = f2bf(v.y); b4.z = f2bf(v.z); b4.w = f2bf(v.w);
    int byte = (r * 128 + kq * 8) ^ ((r & 7) << 4);
    *(s16x4*)((char*)Alds + byte) = b4;
  }
  {
    int jr = t >> 2, qc = t & 3;
#pragma unroll
    for (int q = 0; q < 4; ++q) {
      s16x8 v = *(const s16x8*)(WtK + (size_t)(h * 64 + jr) * MDIM + it * 128 +
                                qc * 32 + q * 8);
#pragma unroll
      for (int e = 0; e < 8; ++e) {
        int i = qc * 32 + q * 8 + e;
        int byte = (i * 128 + jr * 2) ^ ((i & 7) << 4);
        *(short*)((char*)Blds + byte) = v[e];
      }
    }
  }
  __syncthreads();
  f32x4 acc[4][4];
#pragma unroll
  for (int fm = 0; fm < 4; ++fm)
#pragma unroll
    for (int fn = 0; fn < 4; ++fn) acc[fm][fn] = (f32x4)0.0f;
#pragma unroll
  for (int ks = 0; ks < 2; ++ks) {
    int kb = ks * 64 + lg * 16;
    s16x8 af[4];
#pragma unroll
    for (int fm = 0; fm < 4; ++fm) {
      int row = wr * 64 + fm * 16 + li;
      int byte = (row * 128 + kb) ^ ((row & 7) << 4);
      af[fm] = *(s16x8*)((char*)Alds + byte);
    }
#pragma unroll
    for (int fn = 0; fn < 4; ++fn) {
      int col = wc * 64 + fn * 16 + li;
      int byte = (col * 128 + kb) ^ ((col & 7) << 4);
      s16x8 bfv = *(s16x8*)((char*)Blds + byte);
#pragma unroll
      for (int fm = 0; fm < 4; ++fm)
        acc[fm][fn] = __builtin_amdgcn_mfma_f32_16x16x32_bf16(af[fm], bfv,
                                                              acc[fm][fn], 0, 0, 0);
    }
  }
#pragma unroll
  for (int fm = 0; fm < 4; ++fm)
#pragma unroll
    for (int rr = 0; rr < 4; ++rr) {
      int b = bt * 128 + wr * 64 + fm * 16 + lg * 4 + rr;
      short* gp = g + ((size_t)b * 16 + h) * 1024 + it * 128;
#pragma unroll
      for (int fn = 0; fn < 4; ++fn)
        gp[wc * 64 + fn * 16 + li] = f2bf(acc[fm][fn][rr]);
    }
}

// ---------------------------------------------------------------------------
// kW: per batch b: scores = key[b] x g[b] -> softmax -> weights.
// Round-9: Klds double-buffered + 2-deep rA prefetch + ONE barrier per
// K-step; vmcnt never drains to 0 in the loop (T3/T4). WAR on Klds[x] is
// safe: the PREVIOUS sub-step's WAIT_LGKM0+barrier retired all ds_reads of
// Klds[x] (lgkmcnt(0) covers ds_read too) before anyone rewrites it.
// ---------------------------------------------------------------------------
__global__ __launch_bounds__(512) void kW(const float* __restrict__ key,
                                          const short* __restrict__ g,
                                          float* __restrict__ weights) {
  __shared__ alignas(16) short Kl0[128 * 64];    // 16KB
  __shared__ alignas(16) short Kl1[128 * 64];    // 16KB
  __shared__ alignas(16) short Glds[16 * 1024];  // 32KB
  __shared__ float s_lds[16][132];
  int b = blockIdx.x;
  int t = threadIdx.x;
  int wid = t >> 6, lane = t & 63, li = lane & 15, lg = lane >> 4;
  int kq = t & 15, r0s = t >> 4;                 // r0s in [0,32)
  int rcl[4];
#pragma unroll
  for (int i = 0; i < 4; ++i) {
    int r = r0s + 32 * i;
    rcl[i] = r < NTOK ? r : NTOK - 1;
  }
  const float* A = key + (size_t)b * NTOK * MDIM;
  const short* gb = g + (size_t)b * 16384;
  // stage g (bf16) into Glds, swizzled byte ^= (h&7)<<4
#pragma unroll
  for (int q = 0; q < 4; ++q) {
    int c = q * 512 + t;
    s16x8 v = *(const s16x8*)(gb + c * 8);
    int byte = ((c >> 7) * 2048 + (c & 127) * 16) ^ (((c >> 7) & 7) << 4);
    *(s16x8*)((char*)Glds + byte) = v;
  }
  // prologue: rA0 (kt=0), rA1 (kt=1)
  f32x4 rA0[4], rA1[4];
#pragma unroll
  for (int i = 0; i < 4; ++i)
    rA0[i] = *(const f32x4*)(A + (size_t)rcl[i] * MDIM + kq * 4);
#pragma unroll
  for (int i = 0; i < 4; ++i)
    rA1[i] = *(const f32x4*)(A + (size_t)rcl[i] * MDIM + 64 + kq * 4);
  WAIT_LGKM0();                                  // Glds writes done
  __builtin_amdgcn_s_barrier();                  // Glds visible
  f32x4 acc = (f32x4)0.0f;

  for (int kt = 0; kt < 16; kt += 2) {
    // ---- even sub-step: rA0 -> Kl0
    WAIT_VM(4);                                  // rA0 landed; rA1 flying
#pragma unroll
    for (int i = 0; i < 4; ++i) {
      int row = r0s + 32 * i;
      s16x4 b4;
      b4.x = f2bf(rA0[i].x); b4.y = f2bf(rA0[i].y);
      b4.z = f2bf(rA0[i].z); b4.w = f2bf(rA0[i].w);
      int byte = (row * 128 + kq * 8) ^ ((row & 7) << 4);
      *(s16x4*)((char*)Kl0 + byte) = b4;
    }
    {
      int kn = (kt + 2 < 16) ? (kt + 2) * 64 : 0;  // dummy re-read at tail
#pragma unroll
      for (int i = 0; i < 4; ++i)
        rA0[i] = *(const f32x4*)(A + (size_t)rcl[i] * MDIM + kn + kq * 4);
    }
    WAIT_LGKM0();
    __builtin_amdgcn_s_barrier();
#pragma unroll
    for (int ks = 0; ks < 2; ++ks) {
      int kb = ks * 64 + lg * 16;
      int row = wid * 16 + li;
      s16x8 af = *(s16x8*)((char*)Kl0 + ((row * 128 + kb) ^ ((row & 7) << 4)));
      int kel = kt * 64 + ks * 32 + lg * 8;
      s16x8 bf = *(s16x8*)((char*)Glds + ((li * 2048 + kel * 2) ^ ((li & 7) << 4)));
      acc = __builtin_amdgcn_mfma_f32_16x16x32_bf16(af, bf, acc, 0, 0, 0);
    }
    // ---- odd sub-step: rA1 -> Kl1
    WAIT_VM(4);                                  // rA1 landed; rA0(kt+2) flying
#pragma unroll
    for (int i = 0; i < 4; ++i) {
      int row = r0s + 32 * i;
      s16x4 b4;
      b4.x = f2bf(rA1[i].x); b4.y = f2bf(rA1[i].y);
      b4.z = f2bf(rA1[i].z); b4.w = f2bf(rA1[i].w);
      int byte = (row * 128 + kq * 8) ^ ((row & 7) << 4);
      *(s16x4*)((char*)Kl1 + byte) = b4;
    }
    {
      int kn = (kt + 3 < 16) ? (kt + 3) * 64 : 64; // dummy re-read at tail
#pragma unroll
      for (int i = 0; i < 4; ++i)
        rA1[i] = *(const f32x4*)(A + (size_t)rcl[i] * MDIM + kn + kq * 4);
    }
    WAIT_LGKM0();
    __builtin_amdgcn_s_barrier();
#pragma unroll
    for (int ks = 0; ks < 2; ++ks) {
      int kb = ks * 64 + lg * 16;
      int row = wid * 16 + li;
      s16x8 af = *(s16x8*)((char*)Kl1 + ((row * 128 + kb) ^ ((row & 7) << 4)));
      int kel = (kt + 1) * 64 + ks * 32 + lg * 8;
      s16x8 bf = *(s16x8*)((char*)Glds + ((li * 2048 + kel * 2) ^ ((li & 7) << 4)));
      acc = __builtin_amdgcn_mfma_f32_16x16x32_bf16(af, bf, acc, 0, 0, 0);
    }
  }
  // scatter scores: lane holds tokens wid*16+lg*4+rr for head li
#pragma unroll
  for (int rr = 0; rr < 4; ++rr) s_lds[li][wid * 16 + lg * 4 + rr] = acc[rr];
  __syncthreads();
  // softmax: wave wid handles heads 2wid, 2wid+1
#pragma unroll
  for (int hh = 0; hh < 2; ++hh) {
    int h = wid * 2 + hh;
    int n0 = lane, n1 = lane + 64;
    bool v0 = (n0 < NTOK), v1 = (n1 < NTOK);
    float w0, w1;
    if (h == 0 || h == 3) {                      // disturb heads: uniform
      w0 = 1.f / NTOK; w1 = 1.f / NTOK;
    } else {
      const float kinv = 1.f / 32.f;             // 1/sqrt(d*H)
      float s0 = v0 ? s_lds[h][n0] * kinv : -1e30f;
      float s1 = v1 ? s_lds[h][n1] * kinv : -1e30f;
      float m = fmaxf(s0, s1);
#pragma unroll
      for (int msk = 1; msk < 64; msk <<= 1) m = fmaxf(m, __shfl_xor(m, msk));
      float e0 = v0 ? __expf(s0 - m) : 0.f;
      float e1 = v1 ? __expf(s1 - m) : 0.f;
      float s = e0 + e1;
#pragma unroll
      for (int msk = 1; msk < 64; msk <<= 1) s += __shfl_xor(s, msk);
      float inv = 1.f / s;
      w0 = e0 * inv; w1 = e1 * inv;
    }
    float* wp = weights + ((size_t)b * NHEADS + h) * NTOK;
    if (v0) wp[n0] = w0;
    if (v1) wp[n1] = w1;
  }
}

// ---------------------------------------------------------------------------
// kV: vbar[b,h,i] = sum_n weights[b,h,n] * value[b,n,i]  -> bf16 (32MB in ws)
// ---------------------------------------------------------------------------
__global__ __launch_bounds__(512, 4) void kV(const float* __restrict__ value,
                                             const float* __restrict__ weights,
                                             short* __restrict__ vbar) {
  __shared__ float w_lds[16][128];
  int b = blockIdx.x;
  int t = threadIdx.x;
  int grp = t >> 7, ic = t & 127;
#pragma unroll
  for (int q = 0; q < 4; ++q) {
    int idx = q * 512 + t;
    int h = idx >> 7, n = idx & 127;
    w_lds[h][n] = (n < NTOK) ? weights[((size_t)b * NHEADS + h) * NTOK + n] : 0.f;
  }
  __syncthreads();
  const float* V = value + (size_t)b * NTOK * MDIM;
  f32x4 a0[4], a1[4];
#pragma unroll
  for (int hh = 0; hh < 4; ++hh) { a0[hh] = (f32x4)0.0f; a1[hh] = (f32x4)0.0f; }
#pragma unroll 4
  for (int n = 0; n < NTOK; ++n) {
    f32x4 v0 = *(const f32x4*)(V + (size_t)n * MDIM + ic * 8);
    f32x4 v1 = *(const f32x4*)(V + (size_t)n * MDIM + ic * 8 + 4);
#pragma unroll
    for (int hh = 0; hh < 4; ++hh) {
      float wn = w_lds[grp * 4 + hh][n];
      a0[hh] += wn * v0;
      a1[hh] += wn * v1;
    }
  }
#pragma unroll
  for (int hh = 0; hh < 4; ++hh) {
    s16x8 o;
    o[0] = f2bf(a0[hh].x); o[1] = f2bf(a0[hh].y);
    o[2] = f2bf(a0[hh].z); o[3] = f2bf(a0[hh].w);
    o[4] = f2bf(a1[hh].x); o[5] = f2bf(a1[hh].y);
    o[6] = f2bf(a1[hh].z); o[7] = f2bf(a1[hh].w);
    *(s16x8*)(vbar + ((size_t)b * 16 + grp * 4 + hh) * 1024 + ic * 8) = o;
  }
}

// ---------------------------------------------------------------------------
// kO: out[b, h*64+c] = sum_i vbar[b,h,i] * Wv[i, h*64+c] + bv
// All-GLDS staging (round-2 917-TF structure), A = bf16 vbar, B = WtV.
// grid = bt(8) x h(16) = 128 blocks, 256 threads.
// ---------------------------------------------------------------------------
__global__ __launch_bounds__(256, 3) void kO(const short* __restrict__ vbar,
                                             const short* __restrict__ WtV,
                                             const float* __restrict__ bv,
                                             float* __restrict__ outp) {
  __shared__ alignas(16) short Alds[128 * 64];
  __shared__ alignas(16) short Blds[64 * 64];
  int bid = blockIdx.x;
  int bt = bid >> 4, h = bid & 15;
  int t = threadIdx.x;
  int wid = t >> 6, lane = t & 63;
  int wr = wid >> 1, wc = wid & 1, li = lane & 15, lg = lane >> 4;
  f32x4 acc[4][2];
#pragma unroll
  for (int fm = 0; fm < 4; ++fm)
#pragma unroll
    for (int fn = 0; fn < 2; ++fn) acc[fm][fn] = (f32x4)0.0f;

  for (int kt = 0; kt < 16; ++kt) {
    int k0 = kt * 64;
    __syncthreads();                             // prev tile consumed
    // ---- A: vbar rows (batch-local), pre-swizzled source chunks
#pragma unroll
    for (int i = 0; i < 4; ++i) {
      int lrow = wid * 32 + i * 8 + (lane >> 3);
      int jg = (lane & 7) ^ (lrow & 7);
      GLDS(vbar + ((size_t)(bt * 128 + lrow) * 16 + h) * 1024 + k0 + jg * 8,
           Alds + (wid * 32 + i * 8) * 64);
    }
    // ---- B: WtV columns of head h
#pragma unroll
    for (int j = 0; j < 2; ++j) {
      int cl = wid * 16 + j * 8 + (lane >> 3);
      int jg = (lane & 7) ^ (cl & 7);
      GLDS(WtV + (size_t)(h * 64 + cl) * MDIM + k0 + jg * 8,
           Blds + (wid * 16 + j * 8) * 64);
    }
    __syncthreads();                             // drains GLDS
#pragma unroll
    for (int ks = 0; ks < 2; ++ks) {
      int kb = ks * 64 + lg * 16;
      s16x8 af[4];
#pragma unroll
      for (int fm = 0; fm < 4; ++fm) {
        int row = wr * 64 + fm * 16 + li;
        int byte = (row * 128 + kb) ^ ((row & 7) << 4);
        af[fm] = *(s16x8*)((char*)Alds + byte);
      }
#pragma unroll
      for (int fn = 0; fn < 2; ++fn) {
        int col = wc * 32 + fn * 16 + li;
        int byte = (col * 128 + kb) ^ ((col & 7) << 4);
        s16x8 bfv = *(s16x8*)((char*)Blds + byte);
#pragma unroll
        for (int fm = 0; fm < 4; ++fm)
          acc[fm][fn] = __builtin_amdgcn_mfma_f32_16x16x32_bf16(af[fm], bfv,
                                                                acc[fm][fn], 0, 0, 0);
      }
    }
  }
#pragma unroll
  for (int fn = 0; fn < 2; ++fn) {
    int cg = h * 64 + wc * 32 + fn * 16 + li;
    float bvv = bv[cg];
#pragma unroll
    for (int fm = 0; fm < 4; ++fm)
#pragma unroll
      for (int rr = 0; rr < 4; ++rr) {
        int row = bt * 128 + wr * 64 + fm * 16 + lg * 4 + rr;
        outp[(size_t)row * MDIM + cg] = acc[fm][fn][rr] + bvv;
      }
  }
}

// ---------------------------------------------------------------------------
extern "C" void kernel_launch(void* const* d_in, const int* in_sizes, int n_in,
                              void* d_out, int out_size, void* d_ws, size_t ws_size,
                              hipStream_t stream) {
  const float* query = (const float*)d_in[0];
  const float* key   = (const float*)d_in[1];
  const float* value = (const float*)d_in[2];
  const float* Wq    = (const float*)d_in[3];
  const float* bq    = (const float*)d_in[4];
  const float* Wk    = (const float*)d_in[5];
  const float* bk    = (const float*)d_in[6];  // constant per (b,h): cancels in softmax
  const float* Wv    = (const float*)d_in[7];
  const float* bv    = (const float*)d_in[8];
  (void)bk;

  float* out     = (float*)d_out;
  float* weights = out + (size_t)NBATCH * MDIM;

  char* ws = (char*)d_ws;
  short* Wt   = (short*)ws;                               // 6 MB
  float* qp   = (float*)(ws + 6u  * 1024 * 1024);         // 4 MB
  short* g    = (short*)(ws + 10u * 1024 * 1024);         // 32 MB bf16
  short* vbar = (short*)(ws + 48u * 1024 * 1024);         // 32 MB bf16

  kTransW<<<dim3(768),  dim3(256), 0, stream>>>(Wq, Wk, Wv, Wt);
  kQProj <<<dim3(64),   dim3(256), 0, stream>>>(query, Wt, bq, qp);
  kG     <<<dim3(1024), dim3(256), 0, stream>>>(qp, Wt + (size_t)MDIM * MDIM, g);
  kW     <<<dim3(1024), dim3(512), 0, stream>>>(key, g, weights);
  kV     <<<dim3(1024), dim3(512), 0, stream>>>(value, weights, vbar);
  kO     <<<dim3(128),  dim3(256), 0, stream>>>(vbar, Wt + 2 * (size_t)MDIM * MDIM,
                                                bv, out);
}